// Round 12
// baseline (2078.346 us; speedup 1.0000x reference)
//
#include <hip/hip_runtime.h>
#include <hip/hip_bf16.h>
#include <cstdio>

#define Bn 2
#define Cn 512
#define Sn 256
#define En 512

typedef __attribute__((ext_vector_type(8))) short bf16x8;
typedef __attribute__((ext_vector_type(4))) float f32x4;

// Workspace layout (bytes):
//   [0, 2048)        : mean[512] f32 ; [2048,4096): rstd[512] f32
//   byte 1 MiB       : prod f32 [1024][256][256]                   (256 MiB)
//   byte 1MiB+256MiB : vT bf16 tiled [1024][4 fh][4 kt][128][64]   (256 MiB)
//   + ATh, ATl tiled [8 ft][8 et][64][64] bf16 (512 KiB each)
//   + VT tiled [4 fq][8 et][128][64] bf16 (512 KiB)
//   + XNh, XNl tiled [1024 bc][8 et][256][64] bf16 (256 MiB each)
//   smT (bf16 sm, tiled [1024 bc][2 sh][4 kt][128][64]) ALIASES XNl (dead after kscores).
static constexpr size_t PROD_B = (1ull << 20);
static constexpr size_t V_B    = PROD_B + (256ull << 20);
static constexpr size_t ATH_B  = V_B + (256ull << 20);
static constexpr size_t ATL_B  = ATH_B + (512ull << 10);
static constexpr size_t VT_B   = ATL_B + (512ull << 10);
static constexpr size_t XNH_B  = VT_B + (512ull << 10);
static constexpr size_t XNL_B  = XNH_B + (256ull << 20);
static constexpr size_t WS_BIG = XNL_B + (256ull << 20);
static constexpr size_t SMT_B  = XNL_B;  // alias: XNl dead after kscores

__device__ __forceinline__ unsigned short f2bf(float f) {
  union { __hip_bfloat16 h; unsigned short u; } cv;
  cv.h = __float2bfloat16(f);
  return cv.u;
}
__device__ __forceinline__ float bf2f(unsigned short u) {
  union { unsigned int i; float f; } cv;
  cv.i = ((unsigned int)u) << 16;
  return cv.f;
}
__device__ __forceinline__ void split2(float v, unsigned short& h, unsigned short& l) {
  h = f2bf(v);
  l = f2bf(v - bf2f(h));
}
// swizzled ushort index for element (row, col) in a [R][64] tile (byte ^= (row&7)<<4).
__device__ __forceinline__ int swzc(int row, int col) {
  return row * 64 + ((col & 3) | ((col & 60) ^ ((row & 7) << 3)));
}
// MFMA fragment load from a [R][64] swizzled LDS tile: row `row`, k-chunk ks*32+(lane>>4)*8.
__device__ __forceinline__ bf16x8 ldfrag(const unsigned short* arr, int row, int ks, int lane) {
  const int byte = (ks * 64 + ((lane >> 4) << 4)) ^ ((row & 7) << 4);
  return *(const bf16x8*)((const char*)(arr + (size_t)row * 64) + byte);
}
__device__ __forceinline__ f32x4 MFMA(bf16x8 a, bf16x8 b, f32x4 c) {
  return __builtin_amdgcn_mfma_f32_16x16x32_bf16(a, b, c, 0, 0, 0);
}
__device__ __forceinline__ void glds16(const void* g, void* l) {
  __builtin_amdgcn_global_load_lds(
      (const __attribute__((address_space(1))) unsigned int*)g,
      (__attribute__((address_space(3))) unsigned int*)l, 16, 0, 0);
}
// stage nbytes (multiple of 1024) from pre-tiled global (LDS-linear order) into LDS.
__device__ __forceinline__ void stage_tile(const unsigned short* g, unsigned short* l,
                                           int nbytes, int wid, int lane, int nwaves) {
  const char* gb = (const char*)g;
  char* lb = (char*)l;
  for (int j = wid; j < (nbytes >> 10); j += nwaves)
    glds16(gb + j * 1024 + lane * 16, lb + j * 1024);
}

// counted-vmcnt barrier (T4): wait all-but-N vmem, flush lds, barrier, pin order.
#define WAITB(N)                                                   \
  do {                                                             \
    asm volatile("s_waitcnt vmcnt(" #N ")" ::: "memory");          \
    asm volatile("s_waitcnt lgkmcnt(0)" ::: "memory");             \
    __builtin_amdgcn_s_barrier();                                  \
    __builtin_amdgcn_sched_barrier(0);                             \
  } while (0)

// ---------------- K1: per-channel mean / rstd ----------------
__global__ void k1_stats(const float* __restrict__ x, float* __restrict__ ws) {
  const int c = blockIdx.x, tid = threadIdx.x;
  const float4* p0 = (const float4*)(x + (size_t)c * (Sn * En));
  const float4* p1 = (const float4*)(x + (size_t)(Cn + c) * (Sn * En));
  float s1 = 0.f, s2 = 0.f;
  for (int i = tid; i < (Sn * En / 4); i += 256) {
    float4 a = p0[i], b = p1[i];
    s1 += (a.x + a.y) + (a.z + a.w) + (b.x + b.y) + (b.z + b.w);
    s2 += (a.x * a.x + a.y * a.y) + (a.z * a.z + a.w * a.w) +
          (b.x * b.x + b.y * b.y) + (b.z * b.z + b.w * b.w);
  }
  __shared__ float r1[256], r2[256];
  r1[tid] = s1; r2[tid] = s2;
  __syncthreads();
  for (int off = 128; off > 0; off >>= 1) {
    if (tid < off) { r1[tid] += r1[tid + off]; r2[tid] += r2[tid + off]; }
    __syncthreads();
  }
  if (tid == 0) {
    const float n = (float)(2 * Sn * En);
    float mean = r1[0] / n;
    float var = r2[0] / n - mean * mean;
    ws[c] = mean;
    ws[512 + c] = 1.0f / sqrtf(var + 1e-5f);
  }
}

// ---------------- kA: AT = K·Q^T split hi/lo bf16 (tiled); VT = V^T bf16 (tiled) ------
__global__ void kA(const float* __restrict__ Q, const float* __restrict__ K,
                   const float* __restrict__ V, unsigned short* __restrict__ ATh,
                   unsigned short* __restrict__ ATl, unsigned short* __restrict__ VT) {
  const int f = blockIdx.x, tid = threadIdx.x;
  __shared__ float Kf[512];
  for (int i = tid; i < 512; i += 256) Kf[i] = K[(size_t)f * 512 + i];
  __syncthreads();
  const int fr64 = f & 63;
  const size_t atbase = ((size_t)(f >> 6) * 8) * 4096 + (size_t)fr64 * 64;
  const size_t vtbase = ((size_t)(f >> 7) * 8) * 8192 + (size_t)(f & 127) * 64;
#pragma unroll
  for (int half = 0; half < 2; ++half) {
    const int e = tid + half * 256;
    const float* Qe = Q + (size_t)e * 512;
    float acc = 0.f;
    for (int t = 0; t < 512; t += 4) {
      float4 q = *(const float4*)(Qe + t);
      acc += q.x * Kf[t] + q.y * Kf[t + 1] + q.z * Kf[t + 2] + q.w * Kf[t + 3];
    }
    unsigned short h, l;
    split2(acc, h, l);
    const int et = e >> 6, ec = e & 63;
    const int swa = (ec & 3) | ((ec & 60) ^ ((fr64 & 7) << 3));
    ATh[atbase + (size_t)et * 4096 + swa] = h;
    ATl[atbase + (size_t)et * 4096 + swa] = l;
    const int swv = (ec & 3) | ((ec & 60) ^ ((f & 7) << 3));
    VT[vtbase + (size_t)et * 8192 + swv] = f2bf(V[(size_t)e * 512 + f]);
  }
}

// ---------------- kxn: pre-split xn into tiled+swizzled hi/lo bf16 ----------------
__global__ void kxn(const float* __restrict__ x, const float* __restrict__ ws,
                    unsigned short* __restrict__ XNh, unsigned short* __restrict__ XNl) {
  const int bid = blockIdx.x;  // (bc, half)
  const int bc = bid >> 1, half = bid & 1;
  const int c = bc & 511;
  const float mean = ws[c], rstd = ws[512 + c];
  const float* xb = x + (size_t)bc * 131072 + (size_t)half * 128 * 512;
  const int tid = threadIdx.x;
#pragma unroll 4
  for (int i = 0; i < 64; ++i) {
    const int g = tid + i * 256;       // 128 rows x 128 col-groups
    const int r = g >> 7, c4 = g & 127;
    const float4 xv = *(const float4*)(xb + (size_t)r * 512 + c4 * 4);
    ushort4 hv, lv;
    split2((xv.x - mean) * rstd, hv.x, lv.x);
    split2((xv.y - mean) * rstd, hv.y, lv.y);
    split2((xv.z - mean) * rstd, hv.z, lv.z);
    split2((xv.w - mean) * rstd, hv.w, lv.w);
    const int et = c4 >> 4, colt4 = c4 & 15;
    const int row = half * 128 + r;
    const size_t idx = ((size_t)(bc * 8 + et) * 256 + row) * 64 +
                       ((colt4 * 4) ^ ((row & 7) << 3));
    *(ushort4*)&XNh[idx] = hv;
    *(ushort4*)&XNl[idx] = lv;
  }
}

// ---------------- kv_proj: vT[f][t] = sum_e VT[f][e]*xn[t][e]  (dbuf pipeline) -------
__launch_bounds__(256)
__global__ void kv_proj(const unsigned short* __restrict__ VT,
                        const unsigned short* __restrict__ XNh_g,
                        unsigned short* __restrict__ vT_out) {
  __shared__ unsigned short BUF[2][16384];  // each: [VT 8192][XN 8192] = 32 KiB
  const int bid = blockIdx.x;
  const int L = (bid & 7) * 1024 + (bid >> 3);  // chunked XCD swizzle
  const int bc = L >> 3;
  const int fq = (L >> 1) & 3;
  const int th = L & 1;
  const int f0 = fq * 128, t0 = th * 128;
  const int tid = threadIdx.x, w = tid >> 6, lane = tid & 63;

  f32x4 acc[2][8];
#pragma unroll
  for (int i = 0; i < 2; ++i)
#pragma unroll
    for (int j = 0; j < 8; ++j) acc[i][j] = (f32x4){0.f, 0.f, 0.f, 0.f};

  stage_tile(VT + ((size_t)fq * 8 + 0) * 8192, &BUF[0][0], 16384, w, lane, 4);
  stage_tile(XNh_g + ((size_t)(bc * 8 + 0) * 256 + t0) * 64, &BUF[0][8192], 16384, w, lane, 4);
  __syncthreads();
#pragma unroll 1
  for (int et = 0; et < 8; ++et) {
    if (et < 7) {
      const int b = (et + 1) & 1;
      stage_tile(VT + ((size_t)fq * 8 + et + 1) * 8192, &BUF[b][0], 16384, w, lane, 4);
      stage_tile(XNh_g + ((size_t)(bc * 8 + et + 1) * 256 + t0) * 64, &BUF[b][8192],
                 16384, w, lane, 4);
    }
    const unsigned short* cb = &BUF[et & 1][0];
#pragma unroll
    for (int ks = 0; ks < 2; ++ks) {
      bf16x8 a0 = ldfrag(cb, w * 32 + (lane & 15), ks, lane);
      bf16x8 a1 = ldfrag(cb, w * 32 + 16 + (lane & 15), ks, lane);
#pragma unroll
      for (int ct = 0; ct < 8; ++ct) {
        bf16x8 b = ldfrag(cb + 8192, ct * 16 + (lane & 15), ks, lane);
        acc[0][ct] = MFMA(a0, b, acc[0][ct]);
        acc[1][ct] = MFMA(a1, b, acc[1][ct]);
      }
    }
    __syncthreads();
  }
#pragma unroll
  for (int rt = 0; rt < 2; ++rt)
#pragma unroll
    for (int ct = 0; ct < 8; ++ct)
#pragma unroll
      for (int r = 0; r < 4; ++r) {
        const int f = f0 + w * 32 + rt * 16 + (lane >> 4) * 4 + r;
        const int t = t0 + ct * 16 + (lane & 15);
        const size_t idx = (((size_t)bc * 4 + (f >> 7)) * 4 + (t >> 6)) * 8192 +
                           (size_t)(f & 127) * 64 +
                           ((t & 3) | ((t & 60) ^ ((f & 7) << 3)));
        vT_out[idx] = f2bf(acc[rt][ct][r]);
      }
}

// ---------------- kscores: z = (xn·A)·xn^T / sqrt(E), 3-MFMA split ----------------
// grid 2048: (bc, s-half), 8 waves, wave owns 16 s-rows. r11's 48-MFMA coarse phases
// + T4 counted-vmcnt ring-3: uniform 32 KiB slots {AT et-pair (h+l)} / {XN t-half};
// stage for phase g+2 issued in phase g into slot (p+2)%3; barrier = vmcnt(4) (waits
// only the PREVIOUS stage; the just-issued one stays in flight >=1.5 phases). A-frags
// hoisted to phase start BEFORE the glds16 issue (in-order vmcnt retirement => their
// consumption cannot force the new stage to drain). Only the last phase drains to 0.
// LDS = 3x32K STG + 32K YS = 128 KiB. No launch_bounds reg cap (1 blk/CU accepted:
// unified VGPR+AGPR budget ~190/thread pins occupancy regardless).
__launch_bounds__(512)
__global__ void kscores(const unsigned short* __restrict__ ATh_g,
                        const unsigned short* __restrict__ ATl_g,
                        const unsigned short* __restrict__ XNh_g,
                        const unsigned short* __restrict__ XNl_g,
                        float* __restrict__ prod) {
  __shared__ unsigned short STG[3][16384];  // 3 x 32 KiB ring slots: [h 8192][l 8192]
  __shared__ unsigned short YS[8][2048];    // per-wave y scratch: [h 1024][l 1024]
  const int bid = blockIdx.x;
  const int L = (bid & 7) * 256 + (bid >> 3);  // chunked XCD swizzle: s-halves co-XCD
  const int bc = L >> 1, half = L & 1;
  float* prodc = prod + (size_t)bc * 65536 + (size_t)half * 128 * 256;
  const int tid = threadIdx.x, w = tid >> 6, lane = tid & 63;
  const int lr = lane & 15, lk = lane >> 4;

  // ph1 A-frag global addressing (XN stored tiled+swizzled; XOR folded into address)
  const int arow = half * 128 + w * 16 + lr;
  const unsigned short* xnh_row = XNh_g + ((size_t)bc * 8 * 256 + arow) * 64;
  const unsigned short* xnl_row = XNl_g + ((size_t)bc * 8 * 256 + arow) * 64;
  const int ac0 = (lk * 8) ^ ((arow & 7) << 3);       // ks=0 col offset (ushorts)
  const int ac1 = (32 + lk * 8) ^ ((arow & 7) << 3);  // ks=1

  f32x4 accz[16];
#pragma unroll
  for (int i = 0; i < 16; ++i) accz[i] = (f32x4){0.f, 0.f, 0.f, 0.f};
  f32x4 accy[4];
  bf16x8 A[2][2][2];  // [e2][ks][h/l], all statically indexed
  unsigned short* const ys = &YS[w][0];

  // stage an AT et-pair (16K h + 16K l) into ring slot
  auto stAT2 = [&](int ftx, int et2, int slot) {
    stage_tile(ATh_g + ((size_t)ftx * 8 + et2) * 4096, &STG[slot][0], 16384, w, lane, 8);
    stage_tile(ATl_g + ((size_t)ftx * 8 + et2) * 4096, &STG[slot][8192], 16384, w, lane, 8);
  };
  // stage XN t-half (128 rows x 64 e, h + l)
  auto stXT2 = [&](int ftx, int th, int slot) {
    stage_tile(XNh_g + ((size_t)(bc * 8 + ftx) * 256 + th * 128) * 64, &STG[slot][0],
               16384, w, lane, 8);
    stage_tile(XNl_g + ((size_t)(bc * 8 + ftx) * 256 + th * 128) * 64, &STG[slot][8192],
               16384, w, lane, 8);
  };
  // hoisted A-frag loads for an et-pair (8 x 16B per thread)
  auto aload = [&](int et2) {
#pragma unroll
    for (int e2 = 0; e2 < 2; ++e2) {
      const size_t ab = (size_t)(et2 + e2) * 16384;
      A[e2][0][0] = *(const bf16x8*)(xnh_row + ab + ac0);
      A[e2][0][1] = *(const bf16x8*)(xnl_row + ab + ac0);
      A[e2][1][0] = *(const bf16x8*)(xnh_row + ab + ac1);
      A[e2][1][1] = *(const bf16x8*)(xnl_row + ab + ac1);
    }
  };
  // ph1 over the et-pair: accy += xn_srows·AT^T ; A in regs, B from slot
  auto ph1pair = [&](int slot) {
    __builtin_amdgcn_s_setprio(1);
#pragma unroll
    for (int e2 = 0; e2 < 2; ++e2) {
      const unsigned short* Bh = &STG[slot][e2 * 4096];
      const unsigned short* Bl = &STG[slot][8192 + e2 * 4096];
#pragma unroll
      for (int ks = 0; ks < 2; ++ks) {
#pragma unroll
        for (int fc = 0; fc < 4; ++fc) {
          bf16x8 bh = ldfrag(Bh, fc * 16 + lr, ks, lane);
          bf16x8 bl = ldfrag(Bl, fc * 16 + lr, ks, lane);
          accy[fc] = MFMA(A[e2][ks][0], bh, accy[fc]);
          accy[fc] = MFMA(A[e2][ks][0], bl, accy[fc]);
          accy[fc] = MFMA(A[e2][ks][1], bh, accy[fc]);
        }
      }
    }
    __builtin_amdgcn_s_setprio(0);
  };
  // ph2 over a t-half: accz[z0..z0+7] += y·xn_t^T ; A from wave scratch, B from slot
  auto ph2half = [&](int z0, int slot) {
    __builtin_amdgcn_s_setprio(1);
#pragma unroll
    for (int ks = 0; ks < 2; ++ks) {
      bf16x8 yh = ldfrag(ys, lr, ks, lane);
      bf16x8 yl = ldfrag(ys + 1024, lr, ks, lane);
#pragma unroll
      for (int j = 0; j < 8; ++j) {
        bf16x8 bh = ldfrag(&STG[slot][0], j * 16 + lr, ks, lane);
        bf16x8 bl = ldfrag(&STG[slot][8192], j * 16 + lr, ks, lane);
        accz[z0 + j] = MFMA(yh, bh, accz[z0 + j]);
        accz[z0 + j] = MFMA(yh, bl, accz[z0 + j]);
        accz[z0 + j] = MFMA(yl, bh, accz[z0 + j]);
      }
    }
    __builtin_amdgcn_s_setprio(0);
  };
  auto ywrite = [&]() {
#pragma unroll
    for (int fc = 0; fc < 4; ++fc)
#pragma unroll
      for (int r = 0; r < 4; ++r) {
        const int row = lk * 4 + r;
        const int col = fc * 16 + lr;
        unsigned short h, l;
        split2(accy[fc][r], h, l);
        const int idx = swzc(row, col);
        ys[idx] = h;
        ys[1024 + idx] = l;
      }
  };

  // prologue: stages for phases 0 and 1
  stAT2(0, 0, 0);
  stAT2(0, 2, 1);

#pragma unroll 1
  for (int ft = 0; ft < 8; ++ft) {
#pragma unroll
    for (int i = 0; i < 4; ++i) accy[i] = (f32x4){0.f, 0.f, 0.f, 0.f};
    // P0: compute slot0 (AT et0-1); issue (ft,P2)=AT et4-5 -> slot2
    WAITB(4); aload(0); __builtin_amdgcn_sched_barrier(0);
    stAT2(ft, 4, 2); ph1pair(0);
    // P1: slot1 (AT et2-3); issue (ft,P3)=AT et6-7 -> slot0
    WAITB(4); aload(2); __builtin_amdgcn_sched_barrier(0);
    stAT2(ft, 6, 0); ph1pair(1);
    // P2: slot2 (AT et4-5); issue (ft,P4)=XT th0 -> slot1
    WAITB(4); aload(4); __builtin_amdgcn_sched_barrier(0);
    stXT2(ft, 0, 1); ph1pair(2);
    // P3: slot0 (AT et6-7); issue (ft,P5)=XT th1 -> slot2
    WAITB(4); aload(6); __builtin_amdgcn_sched_barrier(0);
    stXT2(ft, 1, 2); ph1pair(0); ywrite();
    // P4: slot1 (XT th0); issue (ft+1,P0)=AT et0-1 -> slot0
    WAITB(4);
    if (ft < 7) stAT2(ft + 1, 0, 0);
    ph2half(0, 1);
    // P5: slot2 (XT th1); issue (ft+1,P1)=AT et2-3 -> slot1
    if (ft < 7) { WAITB(4); stAT2(ft + 1, 2, 1); }
    else        { WAITB(0); }
    ph2half(8, 2);
  }

  const float scale = 0.044194173824159216f;  // 1/sqrt(512)
#pragma unroll
  for (int th = 0; th < 2; ++th)
#pragma unroll
    for (int ct = 0; ct < 8; ++ct)
#pragma unroll
      for (int r = 0; r < 4; ++r) {
        const int row = w * 16 + lk * 4 + r;
        prodc[(size_t)row * 256 + th * 128 + ct * 16 + lr] =
            accz[th * 8 + ct][r] * scale;
      }
}

// ---------------- K3: cross-channel softmax -> bf16 sm in k4-tiled layout ----------
__launch_bounds__(512)
__global__ void k3_softmax(const float* __restrict__ prodf, unsigned short* __restrict__ smT) {
  const int bid = blockIdx.x;  // b*256 + s
  const int b = bid >> 8, s = bid & 255;
  const int tid = threadIdx.x;
  const int t = tid & 255, ch = tid >> 8;
  const float* __restrict__ p =
      prodf + (size_t)b * (512ull * 65536) + (size_t)s * 256 + t + (size_t)ch * 256 * 65536;
  float m = -3.4e38f, sum = 0.f;
#pragma unroll 4
  for (int cc = 0; cc < 256; ++cc) {
    const float v = p[(size_t)cc * 65536];
    if (v > m) { sum *= __expf(m - v); m = v; }
    sum += __expf(v - m);
  }
  __shared__ float Ms[2][256], Ss[2][256];
  Ms[ch][t] = m; Ss[ch][t] = sum;
  __syncthreads();
  const float mo = Ms[ch ^ 1][t], so = Ss[ch ^ 1][t];
  const float mm = fmaxf(m, mo);
  const float inv = 1.0f / (sum * __expf(m - mm) + so * __expf(mo - mm));
  const int sh = s >> 7, r = s & 127, kt = t >> 6, col = t & 63;
  const int cidx = r * 64 + ((col & 3) | ((col & 60) ^ ((r & 7) << 3)));
  const size_t tbase = ((size_t)b * 512 + ch * 256) * 2 + sh;
#pragma unroll 4
  for (int cc = 0; cc < 256; ++cc) {
    const float ev = __expf(p[(size_t)cc * 65536] - mm) * inv;
    smT[((tbase + (size_t)cc * 2) * 4 + kt) * 8192 + cidx] = f2bf(ev);
  }
}

// ---------------- K4: out = sm·v + xn  (bf16 MFMA; residual from XNh bf16) ----------
__launch_bounds__(256)
__global__ void k4_pv(const unsigned short* __restrict__ XNh_g,
                      const unsigned short* __restrict__ vT,
                      const unsigned short* __restrict__ smT,
                      float* __restrict__ out) {
  __shared__ unsigned short BUF[2][16384];  // each: [SM 8192][VT 8192] = 32 KiB
  const int bid = blockIdx.x;
  const int L = (bid & 7) * 1024 + (bid >> 3);  // chunked XCD swizzle
  const int bc = L >> 3;
  const int sh = (L >> 2) & 1;
  const int fh = L & 3;
  const int s0 = sh * 128, f0 = fh * 128;
  const int tid = threadIdx.x, w = tid >> 6, lane = tid & 63;

  f32x4 acc[2][8];
#pragma unroll
  for (int i = 0; i < 2; ++i)
#pragma unroll
    for (int j = 0; j < 8; ++j) acc[i][j] = (f32x4){0.f, 0.f, 0.f, 0.f};

  stage_tile(smT + (((size_t)bc * 2 + sh) * 4 + 0) * 8192, &BUF[0][0], 16384, w, lane, 4);
  stage_tile(vT + (((size_t)bc * 4 + fh) * 4 + 0) * 8192, &BUF[0][8192], 16384, w, lane, 4);
  __syncthreads();
#pragma unroll 1
  for (int kt = 0; kt < 4; ++kt) {
    if (kt < 3) {
      const int b = (kt + 1) & 1;
      stage_tile(smT + (((size_t)bc * 2 + sh) * 4 + kt + 1) * 8192, &BUF[b][0],
                 16384, w, lane, 4);
      stage_tile(vT + (((size_t)bc * 4 + fh) * 4 + kt + 1) * 8192, &BUF[b][8192],
                 16384, w, lane, 4);
    }
    const unsigned short* cb = &BUF[kt & 1][0];
#pragma unroll
    for (int ks = 0; ks < 2; ++ks) {
      bf16x8 a0 = ldfrag(cb, w * 32 + (lane & 15), ks, lane);
      bf16x8 a1 = ldfrag(cb, w * 32 + 16 + (lane & 15), ks, lane);
#pragma unroll
      for (int ct = 0; ct < 8; ++ct) {
        bf16x8 b = ldfrag(cb + 8192, ct * 16 + (lane & 15), ks, lane);
        acc[0][ct] = MFMA(a0, b, acc[0][ct]);
        acc[1][ct] = MFMA(a1, b, acc[1][ct]);
      }
    }
    __syncthreads();
  }
  const int lr = lane & 15, lk = lane >> 4;
#pragma unroll
  for (int rt = 0; rt < 2; ++rt)
#pragma unroll
    for (int ct = 0; ct < 8; ++ct)
#pragma unroll
      for (int r = 0; r < 4; ++r) {
        const int srow = s0 + w * 32 + rt * 16 + lk * 4 + r;
        const int fcol = f0 + ct * 16 + lr;
        const int et = fcol >> 6, col = fcol & 63;
        const unsigned short xh = XNh_g[((size_t)(bc * 8 + et) * 256 + srow) * 64 +
                                        ((col & 3) | ((col & 60) ^ ((srow & 7) << 3)))];
        const size_t oi = (size_t)bc * 131072 + (size_t)srow * 512 + fcol;
        out[oi] = acc[rt][ct][r] + bf2f(xh);
      }
}

extern "C" void kernel_launch(void* const* d_in, const int* in_sizes, int n_in,
                              void* d_out, int out_size, void* d_ws, size_t ws_size,
                              hipStream_t stream) {
  const float* x = (const float*)d_in[0];
  const float* Q = (const float*)d_in[1];
  const float* K = (const float*)d_in[2];
  const float* V = (const float*)d_in[3];
  float* out = (float*)d_out;
  float* ws = (float*)d_ws;
  float* prodf = (float*)((char*)d_ws + PROD_B);
  unsigned short* vT   = (unsigned short*)((char*)d_ws + V_B);
  unsigned short* ATh  = (unsigned short*)((char*)d_ws + ATH_B);
  unsigned short* ATl  = (unsigned short*)((char*)d_ws + ATL_B);
  unsigned short* VTm  = (unsigned short*)((char*)d_ws + VT_B);
  unsigned short* XNh  = (unsigned short*)((char*)d_ws + XNH_B);
  unsigned short* XNl  = (unsigned short*)((char*)d_ws + XNL_B);
  unsigned short* smT  = (unsigned short*)((char*)d_ws + SMT_B);
  if (ws_size < WS_BIG) {
    fprintf(stderr, "kernel_launch: ws_size %zu < needed %zu — expect corruption\n",
            ws_size, WS_BIG);
  }
  k1_stats<<<dim3(512), dim3(256), 0, stream>>>(x, ws);
  kA<<<dim3(512), dim3(256), 0, stream>>>(Q, K, V, ATh, ATl, VTm);
  kxn<<<dim3(2048), dim3(256), 0, stream>>>(x, ws, XNh, XNl);
  kv_proj<<<dim3(8192), dim3(256), 0, stream>>>(VTm, XNh, vT);
  kscores<<<dim3(2048), dim3(512), 0, stream>>>(ATh, ATl, XNh, XNl, prodf);
  k3_softmax<<<dim3(512), dim3(512), 0, stream>>>(prodf, smT);
  k4_pv<<<dim3(8192), dim3(256), 0, stream>>>(XNh, vT, smT, out);
}

// Round 13
// 1968.745 us; speedup vs baseline: 1.0557x; 1.0557x over previous
//
#include <hip/hip_runtime.h>
#include <hip/hip_bf16.h>
#include <cstdio>

#define Bn 2
#define Cn 512
#define Sn 256
#define En 512

typedef __attribute__((ext_vector_type(8))) short bf16x8;
typedef __attribute__((ext_vector_type(4))) float f32x4;

// Workspace layout (bytes):
//   [0, 2048)        : mean[512] f32 ; [2048,4096): rstd[512] f32
//   byte 1 MiB       : prod f32 [1024][256][256]                   (256 MiB)
//   byte 1MiB+256MiB : vT bf16 tiled [1024][4 fh][4 kt][128][64]   (256 MiB)
//   + ATh, ATl tiled [8 ft][8 et][64][64] bf16 (512 KiB each)
//   + VT tiled [4 fq][8 et][128][64] bf16 (512 KiB)
//   + XNh, XNl FRAG-MAJOR: [1024 bc][16 e32][16 rowgrp][64 lane][8 bf16] (256 MiB each)
//     (frag: lane l = (row&15) + (e8)*16 holds elems e32*32+e8*8 .. +8 of row)
//   smT (bf16 sm, tiled [1024 bc][2 sh][4 kt][128][64]) ALIASES XNl (dead after kscores).
static constexpr size_t PROD_B = (1ull << 20);
static constexpr size_t V_B    = PROD_B + (256ull << 20);
static constexpr size_t ATH_B  = V_B + (256ull << 20);
static constexpr size_t ATL_B  = ATH_B + (512ull << 10);
static constexpr size_t VT_B   = ATL_B + (512ull << 10);
static constexpr size_t XNH_B  = VT_B + (512ull << 10);
static constexpr size_t XNL_B  = XNH_B + (256ull << 20);
static constexpr size_t WS_BIG = XNL_B + (256ull << 20);
static constexpr size_t SMT_B  = XNL_B;  // alias: XNl dead after kscores

__device__ __forceinline__ unsigned short f2bf(float f) {
  union { __hip_bfloat16 h; unsigned short u; } cv;
  cv.h = __float2bfloat16(f);
  return cv.u;
}
__device__ __forceinline__ float bf2f(unsigned short u) {
  union { unsigned int i; float f; } cv;
  cv.i = ((unsigned int)u) << 16;
  return cv.f;
}
__device__ __forceinline__ void split2(float v, unsigned short& h, unsigned short& l) {
  h = f2bf(v);
  l = f2bf(v - bf2f(h));
}
// swizzled ushort index for element (row, col) in a [R][64] tile (byte ^= (row&7)<<4).
__device__ __forceinline__ int swzc(int row, int col) {
  return row * 64 + ((col & 3) | ((col & 60) ^ ((row & 7) << 3)));
}
// MFMA fragment load from a [R][64] swizzled LDS tile (AT / VT / SM / Y paths).
__device__ __forceinline__ bf16x8 ldfrag(const unsigned short* arr, int row, int ks, int lane) {
  const int byte = (ks * 64 + ((lane >> 4) << 4)) ^ ((row & 7) << 4);
  return *(const bf16x8*)((const char*)(arr + (size_t)row * 64) + byte);
}
__device__ __forceinline__ f32x4 MFMA(bf16x8 a, bf16x8 b, f32x4 c) {
  return __builtin_amdgcn_mfma_f32_16x16x32_bf16(a, b, c, 0, 0, 0);
}
__device__ __forceinline__ void glds16(const void* g, void* l) {
  __builtin_amdgcn_global_load_lds(
      (const __attribute__((address_space(1))) unsigned int*)g,
      (__attribute__((address_space(3))) unsigned int*)l, 16, 0, 0);
}
// stage nbytes (multiple of 1024) from pre-tiled global (LDS-linear order) into LDS.
__device__ __forceinline__ void stage_tile(const unsigned short* g, unsigned short* l,
                                           int nbytes, int wid, int lane, int nwaves) {
  const char* gb = (const char*)g;
  char* lb = (char*)l;
  for (int j = wid; j < (nbytes >> 10); j += nwaves)
    glds16(gb + j * 1024 + lane * 16, lb + j * 1024);
}

// ---------------- K1: per-channel mean / rstd ----------------
__global__ void k1_stats(const float* __restrict__ x, float* __restrict__ ws) {
  const int c = blockIdx.x, tid = threadIdx.x;
  const float4* p0 = (const float4*)(x + (size_t)c * (Sn * En));
  const float4* p1 = (const float4*)(x + (size_t)(Cn + c) * (Sn * En));
  float s1 = 0.f, s2 = 0.f;
  for (int i = tid; i < (Sn * En / 4); i += 256) {
    float4 a = p0[i], b = p1[i];
    s1 += (a.x + a.y) + (a.z + a.w) + (b.x + b.y) + (b.z + b.w);
    s2 += (a.x * a.x + a.y * a.y) + (a.z * a.z + a.w * a.w) +
          (b.x * b.x + b.y * b.y) + (b.z * b.z + b.w * b.w);
  }
  __shared__ float r1[256], r2[256];
  r1[tid] = s1; r2[tid] = s2;
  __syncthreads();
  for (int off = 128; off > 0; off >>= 1) {
    if (tid < off) { r1[tid] += r1[tid + off]; r2[tid] += r2[tid + off]; }
    __syncthreads();
  }
  if (tid == 0) {
    const float n = (float)(2 * Sn * En);
    float mean = r1[0] / n;
    float var = r2[0] / n - mean * mean;
    ws[c] = mean;
    ws[512 + c] = 1.0f / sqrtf(var + 1e-5f);
  }
}

// ---------------- kA: AT = K·Q^T split hi/lo bf16 (tiled); VT = V^T bf16 (tiled) ------
__global__ void kA(const float* __restrict__ Q, const float* __restrict__ K,
                   const float* __restrict__ V, unsigned short* __restrict__ ATh,
                   unsigned short* __restrict__ ATl, unsigned short* __restrict__ VT) {
  const int f = blockIdx.x, tid = threadIdx.x;
  __shared__ float Kf[512];
  for (int i = tid; i < 512; i += 256) Kf[i] = K[(size_t)f * 512 + i];
  __syncthreads();
  const int fr64 = f & 63;
  const size_t atbase = ((size_t)(f >> 6) * 8) * 4096 + (size_t)fr64 * 64;
  const size_t vtbase = ((size_t)(f >> 7) * 8) * 8192 + (size_t)(f & 127) * 64;
#pragma unroll
  for (int half = 0; half < 2; ++half) {
    const int e = tid + half * 256;
    const float* Qe = Q + (size_t)e * 512;
    float acc = 0.f;
    for (int t = 0; t < 512; t += 4) {
      float4 q = *(const float4*)(Qe + t);
      acc += q.x * Kf[t] + q.y * Kf[t + 1] + q.z * Kf[t + 2] + q.w * Kf[t + 3];
    }
    unsigned short h, l;
    split2(acc, h, l);
    const int et = e >> 6, ec = e & 63;
    const int swa = (ec & 3) | ((ec & 60) ^ ((fr64 & 7) << 3));
    ATh[atbase + (size_t)et * 4096 + swa] = h;
    ATl[atbase + (size_t)et * 4096 + swa] = l;
    const int swv = (ec & 3) | ((ec & 60) ^ ((f & 7) << 3));
    VT[vtbase + (size_t)et * 8192 + swv] = f2bf(V[(size_t)e * 512 + f]);
  }
}

// ---------------- kxn: x -> xn split hi/lo bf16 in FRAG-MAJOR layout ----------------
// Per (bc, half): for each e32 chunk (32 e), LDS-transpose a [128 rows][32 e] f32 tile,
// then each thread emits one 16B frag (8 elems of one row) -> fully coalesced 1KB
// wave stores at [bc][e32][rowgrp][lane].
__global__ void kxn(const float* __restrict__ x, const float* __restrict__ ws,
                    unsigned short* __restrict__ XNh, unsigned short* __restrict__ XNl) {
  __shared__ float xt[128 * 33];
  const int bid = blockIdx.x;  // (bc, half)
  const int bc = bid >> 1, half = bid & 1;
  const int c = bc & 511;
  const float mean = ws[c], rstd = ws[512 + c];
  const float* xb = x + (size_t)bc * 131072 + (size_t)half * 128 * 512;
  const int tid = threadIdx.x;
  const int lane6 = tid & 63;
  const int row15 = lane6 & 15, e8 = lane6 >> 4;

#pragma unroll 1
  for (int e32 = 0; e32 < 16; ++e32) {
    __syncthreads();  // previous iteration's readers done
#pragma unroll
    for (int i = 0; i < 4; ++i) {
      const int g = tid + i * 256;  // 1024 float4 slots: 128 rows x 8 c4
      const int r = g >> 3, c4 = g & 7;
      const float4 v = *(const float4*)(xb + (size_t)r * 512 + e32 * 32 + c4 * 4);
      float* d = &xt[r * 33 + c4 * 4];
      d[0] = v.x; d[1] = v.y; d[2] = v.z; d[3] = v.w;
    }
    __syncthreads();
#pragma unroll
    for (int it = 0; it < 2; ++it) {
      const int rg = (tid >> 6) + it * 4;   // local rowgroup 0..7
      const int row = rg * 16 + row15;
      const float* s = &xt[row * 33 + e8 * 8];
      short hv[8], lv[8];
#pragma unroll
      for (int k = 0; k < 8; ++k) {
        unsigned short h, l;
        split2((s[k] - mean) * rstd, h, l);
        hv[k] = (short)h; lv[k] = (short)l;
      }
      const size_t base =
          ((((size_t)bc * 16 + e32) * 16) + half * 8 + rg) * 512 + (size_t)lane6 * 8;
      *(bf16x8*)&XNh[base] = *(const bf16x8*)hv;
      *(bf16x8*)&XNl[base] = *(const bf16x8*)lv;
    }
  }
}

// ---------------- kv_proj: vT[f][t] = sum_e VT[f][e]*xn[t][e]  (dbuf pipeline) -------
__launch_bounds__(256)
__global__ void kv_proj(const unsigned short* __restrict__ VT,
                        const unsigned short* __restrict__ XNh_g,
                        unsigned short* __restrict__ vT_out) {
  __shared__ unsigned short BUF[2][16384];  // each: [VT 8192][XN 8192] = 32 KiB
  const int bid = blockIdx.x;
  const int L = (bid & 7) * 1024 + (bid >> 3);  // chunked XCD swizzle
  const int bc = L >> 3;
  const int fq = (L >> 1) & 3;
  const int th = L & 1;
  const int f0 = fq * 128, t0 = th * 128;
  const int tid = threadIdx.x, w = tid >> 6, lane = tid & 63;

  f32x4 acc[2][8];
#pragma unroll
  for (int i = 0; i < 2; ++i)
#pragma unroll
    for (int j = 0; j < 8; ++j) acc[i][j] = (f32x4){0.f, 0.f, 0.f, 0.f};

  auto stXN = [&](int et, int b) {  // frag-major: two 8KB chunks (e32 = 2et, 2et+1)
    stage_tile(XNh_g + (((size_t)bc * 16 + et * 2 + 0) * 16 + th * 8) * 512,
               &BUF[b][8192], 8192, w, lane, 4);
    stage_tile(XNh_g + (((size_t)bc * 16 + et * 2 + 1) * 16 + th * 8) * 512,
               &BUF[b][12288], 8192, w, lane, 4);
  };

  stage_tile(VT + ((size_t)fq * 8 + 0) * 8192, &BUF[0][0], 16384, w, lane, 4);
  stXN(0, 0);
  __syncthreads();
#pragma unroll 1
  for (int et = 0; et < 8; ++et) {
    if (et < 7) {
      const int b = (et + 1) & 1;
      stage_tile(VT + ((size_t)fq * 8 + et + 1) * 8192, &BUF[b][0], 16384, w, lane, 4);
      stXN(et + 1, b);
    }
    const unsigned short* cb = &BUF[et & 1][0];
    const char* xnimg = (const char*)(cb + 8192);
#pragma unroll
    for (int ks = 0; ks < 2; ++ks) {
      bf16x8 a0 = ldfrag(cb, w * 32 + (lane & 15), ks, lane);
      bf16x8 a1 = ldfrag(cb, w * 32 + 16 + (lane & 15), ks, lane);
#pragma unroll
      for (int ct = 0; ct < 8; ++ct) {
        bf16x8 b = *(const bf16x8*)(xnimg + ks * 8192 + ct * 1024 + lane * 16);
        acc[0][ct] = MFMA(a0, b, acc[0][ct]);
        acc[1][ct] = MFMA(a1, b, acc[1][ct]);
      }
    }
    __syncthreads();
  }
#pragma unroll
  for (int rt = 0; rt < 2; ++rt)
#pragma unroll
    for (int ct = 0; ct < 8; ++ct)
#pragma unroll
      for (int r = 0; r < 4; ++r) {
        const int f = f0 + w * 32 + rt * 16 + (lane >> 4) * 4 + r;
        const int t = t0 + ct * 16 + (lane & 15);
        const size_t idx = (((size_t)bc * 4 + (f >> 7)) * 4 + (t >> 6)) * 8192 +
                           (size_t)(f & 127) * 64 +
                           ((t & 3) | ((t & 60) ^ ((f & 7) << 3)));
        vT_out[idx] = f2bf(acc[rt][ct][r]);
      }
}

// ---------------- kscores: z = (xn·A)·xn^T / sqrt(E), 3-MFMA split ----------------
// r11 structure EXACTLY (48-MFMA coarse phases, simple __syncthreads dbuf, 48 barriers)
// with XN in frag-major layout: ph1 A-frags are single CONTIGUOUS 1KB wave loads
// (was 128B-strided 16B chunks = ~4x overfetch); ph2 B-frags read lane-contiguous
// from linearly staged XN chunks (no swizzle). AT path unchanged (tiled+swizzled).
__launch_bounds__(512, 2)
__global__ void kscores(const unsigned short* __restrict__ ATh_g,
                        const unsigned short* __restrict__ ATl_g,
                        const unsigned short* __restrict__ XNh_g,
                        const unsigned short* __restrict__ XNl_g,
                        float* __restrict__ prod) {
  __shared__ unsigned short STG[2][16384];  // 32 KiB slots
  __shared__ unsigned short YS[8][2048];    // per-wave y scratch: [h 1024][l 1024]
  const int bid = blockIdx.x;
  const int L = (bid & 7) * 256 + (bid >> 3);  // chunked XCD swizzle: s-halves co-XCD
  const int bc = L >> 1, half = L & 1;
  float* prodc = prod + (size_t)bc * 65536 + (size_t)half * 128 * 256;
  const int tid = threadIdx.x, w = tid >> 6, lane = tid & 63;
  const int lr = lane & 15, lk = lane >> 4;

  // frag-major A addressing: chunk (bc, e32, rowgrp=half*8+w), lane*8 ushorts
  const unsigned short* xnh_bc = XNh_g + ((size_t)bc * 256) * 512;
  const unsigned short* xnl_bc = XNl_g + ((size_t)bc * 256) * 512;
  const int asub = (half * 8 + w) * 512 + lane * 8;  // ushort offset within e32 chunk

  f32x4 accz[16];
#pragma unroll
  for (int i = 0; i < 16; ++i) accz[i] = (f32x4){0.f, 0.f, 0.f, 0.f};
  f32x4 accy[4];
  unsigned short* const ys = &YS[w][0];

  // stage TWO consecutive AT et-tiles: 16K h + 16K l
  auto stAT2 = [&](int ftx, int et2, int p) {
    stage_tile(ATh_g + ((size_t)ftx * 8 + et2) * 4096, STG[p], 16384, w, lane, 8);
    stage_tile(ATl_g + ((size_t)ftx * 8 + et2) * 4096, STG[p] + 8192, 16384, w, lane, 8);
  };
  // stage XN t-half for ft (frag-major): h chunks (e32=2ft,2ft+1), then l
  auto stXT2 = [&](int ftx, int th, int p) {
    stage_tile(XNh_g + (((size_t)bc * 16 + ftx * 2 + 0) * 16 + th * 8) * 512,
               STG[p], 8192, w, lane, 8);
    stage_tile(XNh_g + (((size_t)bc * 16 + ftx * 2 + 1) * 16 + th * 8) * 512,
               STG[p] + 4096, 8192, w, lane, 8);
    stage_tile(XNl_g + (((size_t)bc * 16 + ftx * 2 + 0) * 16 + th * 8) * 512,
               STG[p] + 8192, 8192, w, lane, 8);
    stage_tile(XNl_g + (((size_t)bc * 16 + ftx * 2 + 1) * 16 + th * 8) * 512,
               STG[p] + 12288, 8192, w, lane, 8);
  };
  // ph1 over an et-pair: accy += xn_srows(et)·AT^T ; A coalesced global->reg
  auto ph1pair = [&](int et2, int p) {
    __builtin_amdgcn_s_setprio(1);
#pragma unroll
    for (int e2 = 0; e2 < 2; ++e2) {
      const unsigned short* Bh = STG[p] + e2 * 4096;
      const unsigned short* Bl = STG[p] + 8192 + e2 * 4096;
#pragma unroll
      for (int ks = 0; ks < 2; ++ks) {
        const size_t ch = (size_t)((et2 + e2) * 2 + ks) * 8192;  // e32 chunk (ushorts)
        const bf16x8 ah = *(const bf16x8*)(xnh_bc + ch + asub);
        const bf16x8 al = *(const bf16x8*)(xnl_bc + ch + asub);
#pragma unroll
        for (int fc = 0; fc < 4; ++fc) {
          bf16x8 bh = ldfrag(Bh, fc * 16 + lr, ks, lane);
          bf16x8 bl = ldfrag(Bl, fc * 16 + lr, ks, lane);
          accy[fc] = MFMA(ah, bh, accy[fc]);
          accy[fc] = MFMA(ah, bl, accy[fc]);
          accy[fc] = MFMA(al, bh, accy[fc]);
        }
      }
    }
    __builtin_amdgcn_s_setprio(0);
  };
  // ph2 over a t-half: accz[z0..z0+7] += y·xn_t^T ; B lane-contiguous from staged image
  auto ph2half = [&](int z0, int p) {
    const char* sb = (const char*)&STG[p][0];
    __builtin_amdgcn_s_setprio(1);
#pragma unroll
    for (int ks = 0; ks < 2; ++ks) {
      bf16x8 yh = ldfrag(ys, lr, ks, lane);
      bf16x8 yl = ldfrag(ys + 1024, lr, ks, lane);
#pragma unroll
      for (int j = 0; j < 8; ++j) {
        bf16x8 bh = *(const bf16x8*)(sb + ks * 8192 + j * 1024 + lane * 16);
        bf16x8 bl = *(const bf16x8*)(sb + 16384 + ks * 8192 + j * 1024 + lane * 16);
        accz[z0 + j] = MFMA(yh, bh, accz[z0 + j]);
        accz[z0 + j] = MFMA(yh, bl, accz[z0 + j]);
        accz[z0 + j] = MFMA(yl, bh, accz[z0 + j]);
      }
    }
    __builtin_amdgcn_s_setprio(0);
  };
  auto ywrite = [&]() {
#pragma unroll
    for (int fc = 0; fc < 4; ++fc)
#pragma unroll
      for (int r = 0; r < 4; ++r) {
        const int row = lk * 4 + r;
        const int col = fc * 16 + lr;
        unsigned short h, l;
        split2(accy[fc][r], h, l);
        const int idx = swzc(row, col);
        ys[idx] = h;
        ys[1024 + idx] = l;
      }
  };

  stAT2(0, 0, 0);
  __syncthreads();

#pragma unroll 1
  for (int ft = 0; ft < 8; ++ft) {
#pragma unroll
    for (int i = 0; i < 4; ++i) accy[i] = (f32x4){0.f, 0.f, 0.f, 0.f};
    stAT2(ft, 2, 1);                 ph1pair(0, 0); __syncthreads();
    stAT2(ft, 4, 0);                 ph1pair(2, 1); __syncthreads();
    stAT2(ft, 6, 1);                 ph1pair(4, 0); __syncthreads();
    stXT2(ft, 0, 0);                 ph1pair(6, 1); __syncthreads();
    ywrite();  // wave-private; lgkmcnt auto-inserted before ph2 reads
    stXT2(ft, 1, 1);                 ph2half(0, 0); __syncthreads();
    if (ft < 7) stAT2(ft + 1, 0, 0); ph2half(8, 1); __syncthreads();
  }

  const float scale = 0.044194173824159216f;  // 1/sqrt(512)
#pragma unroll
  for (int th = 0; th < 2; ++th)
#pragma unroll
    for (int ct = 0; ct < 8; ++ct)
#pragma unroll
      for (int r = 0; r < 4; ++r) {
        const int row = w * 16 + lk * 4 + r;
        prodc[(size_t)row * 256 + th * 128 + ct * 16 + lr] =
            accz[th * 8 + ct][r] * scale;
      }
}

// ---------------- K3: cross-channel softmax -> bf16 sm in k4-tiled layout ----------
__launch_bounds__(512)
__global__ void k3_softmax(const float* __restrict__ prodf, unsigned short* __restrict__ smT) {
  const int bid = blockIdx.x;  // b*256 + s
  const int b = bid >> 8, s = bid & 255;
  const int tid = threadIdx.x;
  const int t = tid & 255, ch = tid >> 8;
  const float* __restrict__ p =
      prodf + (size_t)b * (512ull * 65536) + (size_t)s * 256 + t + (size_t)ch * 256 * 65536;
  float m = -3.4e38f, sum = 0.f;
#pragma unroll 4
  for (int cc = 0; cc < 256; ++cc) {
    const float v = p[(size_t)cc * 65536];
    if (v > m) { sum *= __expf(m - v); m = v; }
    sum += __expf(v - m);
  }
  __shared__ float Ms[2][256], Ss[2][256];
  Ms[ch][t] = m; Ss[ch][t] = sum;
  __syncthreads();
  const float mo = Ms[ch ^ 1][t], so = Ss[ch ^ 1][t];
  const float mm = fmaxf(m, mo);
  const float inv = 1.0f / (sum * __expf(m - mm) + so * __expf(mo - mm));
  const int sh = s >> 7, r = s & 127, kt = t >> 6, col = t & 63;
  const int cidx = r * 64 + ((col & 3) | ((col & 60) ^ ((r & 7) << 3)));
  const size_t tbase = ((size_t)b * 512 + ch * 256) * 2 + sh;
#pragma unroll 4
  for (int cc = 0; cc < 256; ++cc) {
    const float ev = __expf(p[(size_t)cc * 65536] - mm) * inv;
    smT[((tbase + (size_t)cc * 2) * 4 + kt) * 8192 + cidx] = f2bf(ev);
  }
}

// ---------------- K4: out = sm·v + xn  (bf16 MFMA; residual from frag-major XNh) -----
__launch_bounds__(256)
__global__ void k4_pv(const unsigned short* __restrict__ XNh_g,
                      const unsigned short* __restrict__ vT,
                      const unsigned short* __restrict__ smT,
                      float* __restrict__ out) {
  __shared__ unsigned short BUF[2][16384];  // each: [SM 8192][VT 8192] = 32 KiB
  const int bid = blockIdx.x;
  const int L = (bid & 7) * 1024 + (bid >> 3);  // chunked XCD swizzle
  const int bc = L >> 3;
  const int sh = (L >> 2) & 1;
  const int fh = L & 3;
  const int s0 = sh * 128, f0 = fh * 128;
  const int tid = threadIdx.x, w = tid >> 6, lane = tid & 63;

  f32x4 acc[2][8];
#pragma unroll
  for (int i = 0; i < 2; ++i)
#pragma unroll
    for (int j = 0; j < 8; ++j) acc[i][j] = (f32x4){0.f, 0.f, 0.f, 0.f};

  stage_tile(smT + (((size_t)bc * 2 + sh) * 4 + 0) * 8192, &BUF[0][0], 16384, w, lane, 4);
  stage_tile(vT + (((size_t)bc * 4 + fh) * 4 + 0) * 8192, &BUF[0][8192], 16384, w, lane, 4);
  __syncthreads();
#pragma unroll 1
  for (int kt = 0; kt < 4; ++kt) {
    if (kt < 3) {
      const int b = (kt + 1) & 1;
      stage_tile(smT + (((size_t)bc * 2 + sh) * 4 + kt + 1) * 8192, &BUF[b][0],
                 16384, w, lane, 4);
      stage_tile(vT + (((size_t)bc * 4 + fh) * 4 + kt + 1) * 8192, &BUF[b][8192],
                 16384, w, lane, 4);
    }
    const unsigned short* cb = &BUF[kt & 1][0];
#pragma unroll
    for (int ks = 0; ks < 2; ++ks) {
      bf16x8 a0 = ldfrag(cb, w * 32 + (lane & 15), ks, lane);
      bf16x8 a1 = ldfrag(cb, w * 32 + 16 + (lane & 15), ks, lane);
#pragma unroll
      for (int ct = 0; ct < 8; ++ct) {
        bf16x8 b = ldfrag(cb + 8192, ct * 16 + (lane & 15), ks, lane);
        acc[0][ct] = MFMA(a0, b, acc[0][ct]);
        acc[1][ct] = MFMA(a1, b, acc[1][ct]);
      }
    }
    __syncthreads();
  }
  const int lr = lane & 15, lk = lane >> 4;
#pragma unroll
  for (int rt = 0; rt < 2; ++rt)
#pragma unroll
    for (int ct = 0; ct < 8; ++ct)
#pragma unroll
      for (int r = 0; r < 4; ++r) {
        const int srow = s0 + w * 32 + rt * 16 + lk * 4 + r;
        const int fcol = f0 + ct * 16 + lr;
        const int e32 = fcol >> 5, e8 = (fcol >> 3) & 3, el = fcol & 7;
        const unsigned short xh =
            XNh_g[(((size_t)bc * 16 + e32) * 16 + (srow >> 4)) * 512 +
                  ((srow & 15) + e8 * 16) * 8 + el];
        const size_t oi = (size_t)bc * 131072 + (size_t)srow * 512 + fcol;
        out[oi] = acc[rt][ct][r] + bf2f(xh);
      }
}

extern "C" void kernel_launch(void* const* d_in, const int* in_sizes, int n_in,
                              void* d_out, int out_size, void* d_ws, size_t ws_size,
                              hipStream_t stream) {
  const float* x = (const float*)d_in[0];
  const float* Q = (const float*)d_in[1];
  const float* K = (const float*)d_in[2];
  const float* V = (const float*)d_in[3];
  float* out = (float*)d_out;
  float* ws = (float*)d_ws;
  float* prodf = (float*)((char*)d_ws + PROD_B);
  unsigned short* vT   = (unsigned short*)((char*)d_ws + V_B);
  unsigned short* ATh  = (unsigned short*)((char*)d_ws + ATH_B);
  unsigned short* ATl  = (unsigned short*)((char*)d_ws + ATL_B);
  unsigned short* VTm  = (unsigned short*)((char*)d_ws + VT_B);
  unsigned short* XNh  = (unsigned short*)((char*)d_ws + XNH_B);
  unsigned short* XNl  = (unsigned short*)((char*)d_ws + XNL_B);
  unsigned short* smT  = (unsigned short*)((char*)d_ws + SMT_B);
  if (ws_size < WS_BIG) {
    fprintf(stderr, "kernel_launch: ws_size %zu < needed %zu — expect corruption\n",
            ws_size, WS_BIG);
  }
  k1_stats<<<dim3(512), dim3(256), 0, stream>>>(x, ws);
  kA<<<dim3(512), dim3(256), 0, stream>>>(Q, K, V, ATh, ATl, VTm);
  kxn<<<dim3(2048), dim3(256), 0, stream>>>(x, ws, XNh, XNl);
  kv_proj<<<dim3(8192), dim3(256), 0, stream>>>(VTm, XNh, vT);
  kscores<<<dim3(2048), dim3(512), 0, stream>>>(ATh, ATl, XNh, XNl, prodf);
  k3_softmax<<<dim3(512), dim3(512), 0, stream>>>(prodf, smT);
  k4_pv<<<dim3(8192), dim3(256), 0, stream>>>(XNh, vT, smT, out);
}

// Round 14
// 1915.773 us; speedup vs baseline: 1.0849x; 1.0277x over previous
//
#include <hip/hip_runtime.h>
#include <hip/hip_bf16.h>
#include <cstdio>

#define Bn 2
#define Cn 512
#define Sn 256
#define En 512

typedef __attribute__((ext_vector_type(8))) short bf16x8;
typedef __attribute__((ext_vector_type(4))) float f32x4;

// Workspace layout (bytes):
//   [0, 2048)        : mean[512] f32 ; [2048,4096): rstd[512] f32
//   byte 1 MiB       : prod f32 [1024][256][256]                   (256 MiB)
//   byte 1MiB+256MiB : vT bf16 tiled [1024][4 fh][4 kt][128][64]   (256 MiB)
//   + ATh, ATl tiled [8 ft][8 et][64][64] bf16 (512 KiB each)
//   + VT tiled [4 fq][8 et][128][64] bf16 (512 KiB)
//   + XNh, XNl tiled [1024 bc][8 et][256][64] bf16 (256 MiB each)
//   smT (bf16 sm, tiled [1024 bc][2 sh][4 kt][128][64]) ALIASES XNl (dead after kscores).
static constexpr size_t PROD_B = (1ull << 20);
static constexpr size_t V_B    = PROD_B + (256ull << 20);
static constexpr size_t ATH_B  = V_B + (256ull << 20);
static constexpr size_t ATL_B  = ATH_B + (512ull << 10);
static constexpr size_t VT_B   = ATL_B + (512ull << 10);
static constexpr size_t XNH_B  = VT_B + (512ull << 10);
static constexpr size_t XNL_B  = XNH_B + (256ull << 20);
static constexpr size_t WS_BIG = XNL_B + (256ull << 20);
static constexpr size_t SMT_B  = XNL_B;  // alias: XNl dead after kscores

__device__ __forceinline__ unsigned short f2bf(float f) {
  union { __hip_bfloat16 h; unsigned short u; } cv;
  cv.h = __float2bfloat16(f);
  return cv.u;
}
__device__ __forceinline__ float bf2f(unsigned short u) {
  union { unsigned int i; float f; } cv;
  cv.i = ((unsigned int)u) << 16;
  return cv.f;
}
__device__ __forceinline__ void split2(float v, unsigned short& h, unsigned short& l) {
  h = f2bf(v);
  l = f2bf(v - bf2f(h));
}
// swizzled ushort index for element (row, col) in a [R][64] tile (byte ^= (row&7)<<4).
__device__ __forceinline__ int swzc(int row, int col) {
  return row * 64 + ((col & 3) | ((col & 60) ^ ((row & 7) << 3)));
}
// MFMA fragment load from a [R][64] swizzled LDS tile: row `row`, k-chunk ks*32+(lane>>4)*8.
__device__ __forceinline__ bf16x8 ldfrag(const unsigned short* arr, int row, int ks, int lane) {
  const int byte = (ks * 64 + ((lane >> 4) << 4)) ^ ((row & 7) << 4);
  return *(const bf16x8*)((const char*)(arr + (size_t)row * 64) + byte);
}
__device__ __forceinline__ f32x4 MFMA(bf16x8 a, bf16x8 b, f32x4 c) {
  return __builtin_amdgcn_mfma_f32_16x16x32_bf16(a, b, c, 0, 0, 0);
}
__device__ __forceinline__ void glds16(const void* g, void* l) {
  __builtin_amdgcn_global_load_lds(
      (const __attribute__((address_space(1))) unsigned int*)g,
      (__attribute__((address_space(3))) unsigned int*)l, 16, 0, 0);
}
// stage nbytes (multiple of 1024) from pre-tiled global (LDS-linear order) into LDS.
__device__ __forceinline__ void stage_tile(const unsigned short* g, unsigned short* l,
                                           int nbytes, int wid, int lane, int nwaves) {
  const char* gb = (const char*)g;
  char* lb = (char*)l;
  for (int j = wid; j < (nbytes >> 10); j += nwaves)
    glds16(gb + j * 1024 + lane * 16, lb + j * 1024);
}

// ---------------- K1: per-channel mean / rstd ----------------
__global__ void k1_stats(const float* __restrict__ x, float* __restrict__ ws) {
  const int c = blockIdx.x, tid = threadIdx.x;
  const float4* p0 = (const float4*)(x + (size_t)c * (Sn * En));
  const float4* p1 = (const float4*)(x + (size_t)(Cn + c) * (Sn * En));
  float s1 = 0.f, s2 = 0.f;
  for (int i = tid; i < (Sn * En / 4); i += 256) {
    float4 a = p0[i], b = p1[i];
    s1 += (a.x + a.y) + (a.z + a.w) + (b.x + b.y) + (b.z + b.w);
    s2 += (a.x * a.x + a.y * a.y) + (a.z * a.z + a.w * a.w) +
          (b.x * b.x + b.y * b.y) + (b.z * b.z + b.w * b.w);
  }
  __shared__ float r1[256], r2[256];
  r1[tid] = s1; r2[tid] = s2;
  __syncthreads();
  for (int off = 128; off > 0; off >>= 1) {
    if (tid < off) { r1[tid] += r1[tid + off]; r2[tid] += r2[tid + off]; }
    __syncthreads();
  }
  if (tid == 0) {
    const float n = (float)(2 * Sn * En);
    float mean = r1[0] / n;
    float var = r2[0] / n - mean * mean;
    ws[c] = mean;
    ws[512 + c] = 1.0f / sqrtf(var + 1e-5f);
  }
}

// ---------------- kA: AT = K·Q^T split hi/lo bf16 (tiled); VT = V^T bf16 (tiled) ------
__global__ void kA(const float* __restrict__ Q, const float* __restrict__ K,
                   const float* __restrict__ V, unsigned short* __restrict__ ATh,
                   unsigned short* __restrict__ ATl, unsigned short* __restrict__ VT) {
  const int f = blockIdx.x, tid = threadIdx.x;
  __shared__ float Kf[512];
  for (int i = tid; i < 512; i += 256) Kf[i] = K[(size_t)f * 512 + i];
  __syncthreads();
  const int fr64 = f & 63;
  const size_t atbase = ((size_t)(f >> 6) * 8) * 4096 + (size_t)fr64 * 64;
  const size_t vtbase = ((size_t)(f >> 7) * 8) * 8192 + (size_t)(f & 127) * 64;
#pragma unroll
  for (int half = 0; half < 2; ++half) {
    const int e = tid + half * 256;
    const float* Qe = Q + (size_t)e * 512;
    float acc = 0.f;
    for (int t = 0; t < 512; t += 4) {
      float4 q = *(const float4*)(Qe + t);
      acc += q.x * Kf[t] + q.y * Kf[t + 1] + q.z * Kf[t + 2] + q.w * Kf[t + 3];
    }
    unsigned short h, l;
    split2(acc, h, l);
    const int et = e >> 6, ec = e & 63;
    const int swa = (ec & 3) | ((ec & 60) ^ ((fr64 & 7) << 3));
    ATh[atbase + (size_t)et * 4096 + swa] = h;
    ATl[atbase + (size_t)et * 4096 + swa] = l;
    const int swv = (ec & 3) | ((ec & 60) ^ ((f & 7) << 3));
    VT[vtbase + (size_t)et * 8192 + swv] = f2bf(V[(size_t)e * 512 + f]);
  }
}

// ---------------- kxn: pre-split xn into tiled+swizzled hi/lo bf16 ----------------
__global__ void kxn(const float* __restrict__ x, const float* __restrict__ ws,
                    unsigned short* __restrict__ XNh, unsigned short* __restrict__ XNl) {
  const int bid = blockIdx.x;  // (bc, half)
  const int bc = bid >> 1, half = bid & 1;
  const int c = bc & 511;
  const float mean = ws[c], rstd = ws[512 + c];
  const float* xb = x + (size_t)bc * 131072 + (size_t)half * 128 * 512;
  const int tid = threadIdx.x;
#pragma unroll 4
  for (int i = 0; i < 64; ++i) {
    const int g = tid + i * 256;       // 128 rows x 128 col-groups
    const int r = g >> 7, c4 = g & 127;
    const float4 xv = *(const float4*)(xb + (size_t)r * 512 + c4 * 4);
    ushort4 hv, lv;
    split2((xv.x - mean) * rstd, hv.x, lv.x);
    split2((xv.y - mean) * rstd, hv.y, lv.y);
    split2((xv.z - mean) * rstd, hv.z, lv.z);
    split2((xv.w - mean) * rstd, hv.w, lv.w);
    const int et = c4 >> 4, colt4 = c4 & 15;
    const int row = half * 128 + r;
    const size_t idx = ((size_t)(bc * 8 + et) * 256 + row) * 64 +
                       ((colt4 * 4) ^ ((row & 7) << 3));
    *(ushort4*)&XNh[idx] = hv;
    *(ushort4*)&XNl[idx] = lv;
  }
}

// ---------------- kv_proj: vT[f][t] = sum_e VT[f][e]*xn[t][e]  (fq-loop, dbuf) -------
// grid 2048 = (bc, th): the fq loop moved INSIDE the block so each block reads its
// XN t-half ONCE per fq with L2 reuse across fq (XN HBM traffic 1 GB -> 256 MB).
// Same r11 per-phase shape: 32 KiB dbuf slots {VT slab 16K | XN slab 16K}, 32 MFMA.
__launch_bounds__(256)
__global__ void kv_proj(const unsigned short* __restrict__ VT,
                        const unsigned short* __restrict__ XNh_g,
                        unsigned short* __restrict__ vT_out) {
  __shared__ unsigned short BUF[2][16384];  // each: [VT 8192][XN 8192] = 32 KiB
  const int bid = blockIdx.x;
  const int L = (bid & 7) * 256 + (bid >> 3);  // chunked XCD swizzle (2048 % 8 == 0)
  const int bc = L >> 1;
  const int th = L & 1;
  const int t0 = th * 128;
  const int tid = threadIdx.x, w = tid >> 6, lane = tid & 63;

  auto stage_pair = [&](int fq, int et, int b) {
    stage_tile(VT + ((size_t)fq * 8 + et) * 8192, &BUF[b][0], 16384, w, lane, 4);
    stage_tile(XNh_g + ((size_t)(bc * 8 + et) * 256 + t0) * 64, &BUF[b][8192],
               16384, w, lane, 4);
  };

  stage_pair(0, 0, 0);
  __syncthreads();
#pragma unroll 1
  for (int fq = 0; fq < 4; ++fq) {
    const int f0 = fq * 128;
    f32x4 acc[2][8];
#pragma unroll
    for (int i = 0; i < 2; ++i)
#pragma unroll
      for (int j = 0; j < 8; ++j) acc[i][j] = (f32x4){0.f, 0.f, 0.f, 0.f};

#pragma unroll 1
    for (int et = 0; et < 8; ++et) {
      const int idx = fq * 8 + et;
      if (idx < 31) stage_pair((idx + 1) >> 3, (idx + 1) & 7, (idx + 1) & 1);
      const unsigned short* cb = &BUF[idx & 1][0];
#pragma unroll
      for (int ks = 0; ks < 2; ++ks) {
        bf16x8 a0 = ldfrag(cb, w * 32 + (lane & 15), ks, lane);
        bf16x8 a1 = ldfrag(cb, w * 32 + 16 + (lane & 15), ks, lane);
#pragma unroll
        for (int ct = 0; ct < 8; ++ct) {
          bf16x8 b = ldfrag(cb + 8192, ct * 16 + (lane & 15), ks, lane);
          acc[0][ct] = MFMA(a0, b, acc[0][ct]);
          acc[1][ct] = MFMA(a1, b, acc[1][ct]);
        }
      }
      __syncthreads();
    }
#pragma unroll
    for (int rt = 0; rt < 2; ++rt)
#pragma unroll
      for (int ct = 0; ct < 8; ++ct)
#pragma unroll
        for (int r = 0; r < 4; ++r) {
          const int f = f0 + w * 32 + rt * 16 + (lane >> 4) * 4 + r;
          const int t = t0 + ct * 16 + (lane & 15);
          const size_t idx = (((size_t)bc * 4 + (f >> 7)) * 4 + (t >> 6)) * 8192 +
                             (size_t)(f & 127) * 64 +
                             ((t & 3) | ((t & 60) ^ ((f & 7) << 3)));
          vT_out[idx] = f2bf(acc[rt][ct][r]);
        }
  }
}

// ---------------- kscores: z = (xn·A)·xn^T / sqrt(E), 3-MFMA split (r11-exact) -------
// 48-MFMA coarse phases, simple __syncthreads dbuf, 6 barriers/ft. ph1 A-side
// wave-private global->reg; all B-operands via LDS. LB(512,2) = VGPR<=128.
__launch_bounds__(512, 2)
__global__ void kscores(const unsigned short* __restrict__ ATh_g,
                        const unsigned short* __restrict__ ATl_g,
                        const unsigned short* __restrict__ XNh_g,
                        const unsigned short* __restrict__ XNl_g,
                        float* __restrict__ prod) {
  __shared__ unsigned short STG[2][16384];  // 32 KiB slots: [h 8192][l 8192] ushorts
  __shared__ unsigned short YS[8][2048];    // per-wave y scratch: [h 1024][l 1024]
  const int bid = blockIdx.x;
  const int L = (bid & 7) * 256 + (bid >> 3);  // chunked XCD swizzle: s-halves co-XCD
  const int bc = L >> 1, half = L & 1;
  float* prodc = prod + (size_t)bc * 65536 + (size_t)half * 128 * 256;
  const int tid = threadIdx.x, w = tid >> 6, lane = tid & 63;
  const int lr = lane & 15, lk = lane >> 4;

  const int arow = half * 128 + w * 16 + lr;
  const unsigned short* xnh_row = XNh_g + ((size_t)bc * 8 * 256 + arow) * 64;
  const unsigned short* xnl_row = XNl_g + ((size_t)bc * 8 * 256 + arow) * 64;
  const int ac0 = (lk * 8) ^ ((arow & 7) << 3);       // ks=0 col offset (ushorts)
  const int ac1 = (32 + lk * 8) ^ ((arow & 7) << 3);  // ks=1

  f32x4 accz[16];
#pragma unroll
  for (int i = 0; i < 16; ++i) accz[i] = (f32x4){0.f, 0.f, 0.f, 0.f};
  f32x4 accy[4];
  unsigned short* const ys = &YS[w][0];

  auto stAT2 = [&](int ftx, int et2, int p) {
    stage_tile(ATh_g + ((size_t)ftx * 8 + et2) * 4096, STG[p], 16384, w, lane, 8);
    stage_tile(ATl_g + ((size_t)ftx * 8 + et2) * 4096, STG[p] + 8192, 16384, w, lane, 8);
  };
  auto stXT2 = [&](int ftx, int th, int p) {
    stage_tile(XNh_g + ((size_t)(bc * 8 + ftx) * 256 + th * 128) * 64, STG[p],
               16384, w, lane, 8);
    stage_tile(XNl_g + ((size_t)(bc * 8 + ftx) * 256 + th * 128) * 64, STG[p] + 8192,
               16384, w, lane, 8);
  };
  auto ph1pair = [&](int et2, int p) {
    __builtin_amdgcn_s_setprio(1);
#pragma unroll
    for (int e2 = 0; e2 < 2; ++e2) {
      const unsigned short* Bh = STG[p] + e2 * 4096;
      const unsigned short* Bl = STG[p] + 8192 + e2 * 4096;
      const size_t abase = (size_t)(et2 + e2) * 16384;
#pragma unroll
      for (int ks = 0; ks < 2; ++ks) {
        const int ac = ks ? ac1 : ac0;
        const bf16x8 ah = *(const bf16x8*)(xnh_row + abase + ac);
        const bf16x8 al = *(const bf16x8*)(xnl_row + abase + ac);
#pragma unroll
        for (int fc = 0; fc < 4; ++fc) {
          bf16x8 bh = ldfrag(Bh, fc * 16 + lr, ks, lane);
          bf16x8 bl = ldfrag(Bl, fc * 16 + lr, ks, lane);
          accy[fc] = MFMA(ah, bh, accy[fc]);
          accy[fc] = MFMA(ah, bl, accy[fc]);
          accy[fc] = MFMA(al, bh, accy[fc]);
        }
      }
    }
    __builtin_amdgcn_s_setprio(0);
  };
  auto ph2half = [&](int z0, int p) {
    __builtin_amdgcn_s_setprio(1);
#pragma unroll
    for (int ks = 0; ks < 2; ++ks) {
      bf16x8 yh = ldfrag(ys, lr, ks, lane);
      bf16x8 yl = ldfrag(ys + 1024, lr, ks, lane);
#pragma unroll
      for (int j = 0; j < 8; ++j) {
        bf16x8 bh = ldfrag(STG[p], j * 16 + lr, ks, lane);
        bf16x8 bl = ldfrag(STG[p] + 8192, j * 16 + lr, ks, lane);
        accz[z0 + j] = MFMA(yh, bh, accz[z0 + j]);
        accz[z0 + j] = MFMA(yh, bl, accz[z0 + j]);
        accz[z0 + j] = MFMA(yl, bh, accz[z0 + j]);
      }
    }
    __builtin_amdgcn_s_setprio(0);
  };
  auto ywrite = [&]() {
#pragma unroll
    for (int fc = 0; fc < 4; ++fc)
#pragma unroll
      for (int r = 0; r < 4; ++r) {
        const int row = lk * 4 + r;
        const int col = fc * 16 + lr;
        unsigned short h, l;
        split2(accy[fc][r], h, l);
        const int idx = swzc(row, col);
        ys[idx] = h;
        ys[1024 + idx] = l;
      }
  };

  stAT2(0, 0, 0);
  __syncthreads();

#pragma unroll 1
  for (int ft = 0; ft < 8; ++ft) {
#pragma unroll
    for (int i = 0; i < 4; ++i) accy[i] = (f32x4){0.f, 0.f, 0.f, 0.f};
    stAT2(ft, 2, 1);                 ph1pair(0, 0); __syncthreads();
    stAT2(ft, 4, 0);                 ph1pair(2, 1); __syncthreads();
    stAT2(ft, 6, 1);                 ph1pair(4, 0); __syncthreads();
    stXT2(ft, 0, 0);                 ph1pair(6, 1); __syncthreads();
    ywrite();  // wave-private; lgkmcnt auto-inserted before ph2 reads
    stXT2(ft, 1, 1);                 ph2half(0, 0); __syncthreads();
    if (ft < 7) stAT2(ft + 1, 0, 0); ph2half(8, 1); __syncthreads();
  }

  const float scale = 0.044194173824159216f;  // 1/sqrt(512)
#pragma unroll
  for (int th = 0; th < 2; ++th)
#pragma unroll
    for (int ct = 0; ct < 8; ++ct)
#pragma unroll
      for (int r = 0; r < 4; ++r) {
        const int row = w * 16 + lk * 4 + r;
        prodc[(size_t)row * 256 + th * 128 + ct * 16 + lr] =
            accz[th * 8 + ct][r] * scale;
      }
}

// ---------------- K3: cross-channel softmax -> bf16 sm in k4-tiled layout ----------
__launch_bounds__(512)
__global__ void k3_softmax(const float* __restrict__ prodf, unsigned short* __restrict__ smT) {
  const int bid = blockIdx.x;  // b*256 + s
  const int b = bid >> 8, s = bid & 255;
  const int tid = threadIdx.x;
  const int t = tid & 255, ch = tid >> 8;
  const float* __restrict__ p =
      prodf + (size_t)b * (512ull * 65536) + (size_t)s * 256 + t + (size_t)ch * 256 * 65536;
  float m = -3.4e38f, sum = 0.f;
#pragma unroll 4
  for (int cc = 0; cc < 256; ++cc) {
    const float v = p[(size_t)cc * 65536];
    if (v > m) { sum *= __expf(m - v); m = v; }
    sum += __expf(v - m);
  }
  __shared__ float Ms[2][256], Ss[2][256];
  Ms[ch][t] = m; Ss[ch][t] = sum;
  __syncthreads();
  const float mo = Ms[ch ^ 1][t], so = Ss[ch ^ 1][t];
  const float mm = fmaxf(m, mo);
  const float inv = 1.0f / (sum * __expf(m - mm) + so * __expf(mo - mm));
  const int sh = s >> 7, r = s & 127, kt = t >> 6, col = t & 63;
  const int cidx = r * 64 + ((col & 3) | ((col & 60) ^ ((r & 7) << 3)));
  const size_t tbase = ((size_t)b * 512 + ch * 256) * 2 + sh;
#pragma unroll 4
  for (int cc = 0; cc < 256; ++cc) {
    const float ev = __expf(p[(size_t)cc * 65536] - mm) * inv;
    smT[((tbase + (size_t)cc * 2) * 4 + kt) * 8192 + cidx] = f2bf(ev);
  }
}

// ---------------- K4: out = sm·v + xn  (bf16 MFMA; residual from x, coalesced) -------
__launch_bounds__(256)
__global__ void k4_pv(const float* __restrict__ x, const float* __restrict__ ws,
                      const unsigned short* __restrict__ vT,
                      const unsigned short* __restrict__ smT,
                      float* __restrict__ out) {
  __shared__ unsigned short BUF[2][16384];  // each: [SM 8192][VT 8192] = 32 KiB
  const int bid = blockIdx.x;
  const int L = (bid & 7) * 1024 + (bid >> 3);  // chunked XCD swizzle
  const int bc = L >> 3;
  const int sh = (L >> 2) & 1;
  const int fh = L & 3;
  const int c = bc & 511;
  const float mean = ws[c], rstd = ws[512 + c];
  const int s0 = sh * 128, f0 = fh * 128;
  const int tid = threadIdx.x, w = tid >> 6, lane = tid & 63;

  f32x4 acc[2][8];
#pragma unroll
  for (int i = 0; i < 2; ++i)
#pragma unroll
    for (int j = 0; j < 8; ++j) acc[i][j] = (f32x4){0.f, 0.f, 0.f, 0.f};

  stage_tile(smT + (((size_t)bc * 2 + sh) * 4 + 0) * 8192, &BUF[0][0], 16384, w, lane, 4);
  stage_tile(vT + (((size_t)bc * 4 + fh) * 4 + 0) * 8192, &BUF[0][8192], 16384, w, lane, 4);
  __syncthreads();
#pragma unroll 1
  for (int kt = 0; kt < 4; ++kt) {
    if (kt < 3) {
      const int b = (kt + 1) & 1;
      stage_tile(smT + (((size_t)bc * 2 + sh) * 4 + kt + 1) * 8192, &BUF[b][0],
                 16384, w, lane, 4);
      stage_tile(vT + (((size_t)bc * 4 + fh) * 4 + kt + 1) * 8192, &BUF[b][8192],
                 16384, w, lane, 4);
    }
    const unsigned short* cb = &BUF[kt & 1][0];
#pragma unroll
    for (int ks = 0; ks < 2; ++ks) {
      bf16x8 a0 = ldfrag(cb, w * 32 + (lane & 15), ks, lane);
      bf16x8 a1 = ldfrag(cb, w * 32 + 16 + (lane & 15), ks, lane);
#pragma unroll
      for (int ct = 0; ct < 8; ++ct) {
        bf16x8 b = ldfrag(cb + 8192, ct * 16 + (lane & 15), ks, lane);
        acc[0][ct] = MFMA(a0, b, acc[0][ct]);
        acc[1][ct] = MFMA(a1, b, acc[1][ct]);
      }
    }
    __syncthreads();
  }
  const int lr = lane & 15, lk = lane >> 4;
#pragma unroll
  for (int rt = 0; rt < 2; ++rt)
#pragma unroll
    for (int ct = 0; ct < 8; ++ct)
#pragma unroll
      for (int r = 0; r < 4; ++r) {
        const int srow = s0 + w * 32 + rt * 16 + lk * 4 + r;
        const int fcol = f0 + ct * 16 + lr;
        const size_t oi = (size_t)bc * 131072 + (size_t)srow * 512 + fcol;
        out[oi] = acc[rt][ct][r] + (x[oi] - mean) * rstd;
      }
}

extern "C" void kernel_launch(void* const* d_in, const int* in_sizes, int n_in,
                              void* d_out, int out_size, void* d_ws, size_t ws_size,
                              hipStream_t stream) {
  const float* x = (const float*)d_in[0];
  const float* Q = (const float*)d_in[1];
  const float* K = (const float*)d_in[2];
  const float* V = (const float*)d_in[3];
  float* out = (float*)d_out;
  float* ws = (float*)d_ws;
  float* prodf = (float*)((char*)d_ws + PROD_B);
  unsigned short* vT   = (unsigned short*)((char*)d_ws + V_B);
  unsigned short* ATh  = (unsigned short*)((char*)d_ws + ATH_B);
  unsigned short* ATl  = (unsigned short*)((char*)d_ws + ATL_B);
  unsigned short* VTm  = (unsigned short*)((char*)d_ws + VT_B);
  unsigned short* XNh  = (unsigned short*)((char*)d_ws + XNH_B);
  unsigned short* XNl  = (unsigned short*)((char*)d_ws + XNL_B);
  unsigned short* smT  = (unsigned short*)((char*)d_ws + SMT_B);
  if (ws_size < WS_BIG) {
    fprintf(stderr, "kernel_launch: ws_size %zu < needed %zu — expect corruption\n",
            ws_size, WS_BIG);
  }
  k1_stats<<<dim3(512), dim3(256), 0, stream>>>(x, ws);
  kA<<<dim3(512), dim3(256), 0, stream>>>(Q, K, V, ATh, ATl, VTm);
  kxn<<<dim3(2048), dim3(256), 0, stream>>>(x, ws, XNh, XNl);
  kv_proj<<<dim3(2048), dim3(256), 0, stream>>>(VTm, XNh, vT);
  kscores<<<dim3(2048), dim3(512), 0, stream>>>(ATh, ATl, XNh, XNl, prodf);
  k3_softmax<<<dim3(512), dim3(512), 0, stream>>>(prodf, smT);
  k4_pv<<<dim3(8192), dim3(256), 0, stream>>>(x, ws, vT, smT, out);
}